// Round 2
// baseline (220.165 us; speedup 1.0000x reference)
//
#include <hip/hip_runtime.h>
#include <hip/hip_bf16.h>

#define B_ 4
#define N_ 4096
#define C_ 64

constexpr float LOG2E = 1.44269504088896340736f;

typedef __attribute__((ext_vector_type(8))) short short8;
typedef __attribute__((ext_vector_type(4))) float f32x4;

#if __has_builtin(__builtin_amdgcn_exp2f)
#define EXP2F(x) __builtin_amdgcn_exp2f(x)
#else
#define EXP2F(x) exp2f(x)
#endif

static __device__ inline short f32_to_bf16_bits(float f) {
    union { __hip_bfloat16 h; unsigned short u; } cv;
    cv.h = __float2bfloat16(f);
    return (short)cv.u;
}

// ---------------------------------------------------------------------------
// Fused prep: per (b, 64-row tile):
//   s1[b,i] = (h[b,i,:]@a1)*log2e ; s2 likewise
//   hT[b][c][j] = bf16(h[b][j][c])
// ---------------------------------------------------------------------------
__global__ __launch_bounds__(256) void gat_prep(
    const float* __restrict__ h, const float* __restrict__ a,
    float* __restrict__ s1s, float* __restrict__ s2s,
    unsigned short* __restrict__ hT)
{
    const int bid = blockIdx.x;                 // B * N/64 = 256
    const int b = bid >> 6;
    const int i0 = (bid & 63) * 64;
    __shared__ float tile[64][65];
    const int t = threadIdx.x;
    {
        const int rr = t >> 2;                  // local row (j)
        const int cc = (t & 3) * 16;            // channel chunk
        const float* src = h + ((size_t)(b * N_ + i0 + rr)) * C_ + cc;
        float d1 = 0.f, d2 = 0.f;
#pragma unroll
        for (int k = 0; k < 16; k += 4) {
            float4 v = *(const float4*)(src + k);
            tile[rr][cc + k + 0] = v.x;
            tile[rr][cc + k + 1] = v.y;
            tile[rr][cc + k + 2] = v.z;
            tile[rr][cc + k + 3] = v.w;
            float4 a1 = *(const float4*)(a + cc + k);
            float4 a2 = *(const float4*)(a + C_ + cc + k);
            d1 += v.x * a1.x + v.y * a1.y + v.z * a1.z + v.w * a1.w;
            d2 += v.x * a2.x + v.y * a2.y + v.z * a2.z + v.w * a2.w;
        }
        // 4 consecutive lanes hold partial dots of the same row
        d1 += __shfl_xor(d1, 1, 64); d1 += __shfl_xor(d1, 2, 64);
        d2 += __shfl_xor(d2, 1, 64); d2 += __shfl_xor(d2, 2, 64);
        if ((t & 3) == 0) {
            s1s[b * N_ + i0 + rr] = d1 * LOG2E;
            s2s[b * N_ + i0 + rr] = d2 * LOG2E;
        }
    }
    __syncthreads();
    {
        const int c  = t >> 2;                  // channel
        const int ic = (t & 3) * 16;            // j chunk
        short8 w0, w1;
#pragma unroll
        for (int k = 0; k < 8; ++k)
            w0[k] = f32_to_bf16_bits(tile[ic + k][c]);
#pragma unroll
        for (int k = 0; k < 8; ++k)
            w1[k] = f32_to_bf16_bits(tile[ic + 8 + k][c]);
        unsigned short* dst = hT + ((size_t)(b * C_ + c)) * N_ + i0 + ic;
        *(short8*)(dst)     = w0;
        *(short8*)(dst + 8) = w1;
    }
}

// ---------------------------------------------------------------------------
// Main kernel: masked-softmax numerator + PV with fixed zero max reference.
// ITILE=32 rows/wave. Grid: 128 i-tiles * jsNum j-splits. 4 waves = 4 batches.
// Software double-buffered j-tiles (two named register tiles, static indexing).
// ---------------------------------------------------------------------------
struct JTile {
    short8 bfrag[4];
    float  s2v[8];
    float  adjv[2][8];
};

static __device__ inline void load_tile(
    JTile& T, const unsigned short* __restrict__ hTb,
    const float* __restrict__ s2b,
    const float* __restrict__ adjR0, const float* __restrict__ adjR1,
    int kb, int r16)
{
#pragma unroll
    for (int ct = 0; ct < 4; ++ct)
        T.bfrag[ct] = *(const short8*)(hTb + (size_t)(ct * 16 + r16) * N_ + kb);
    float4 sa = *(const float4*)(s2b + kb);
    float4 sb = *(const float4*)(s2b + kb + 4);
    T.s2v[0] = sa.x; T.s2v[1] = sa.y; T.s2v[2] = sa.z; T.s2v[3] = sa.w;
    T.s2v[4] = sb.x; T.s2v[5] = sb.y; T.s2v[6] = sb.z; T.s2v[7] = sb.w;
    float4 a0 = *(const float4*)(adjR0 + kb);
    float4 a1 = *(const float4*)(adjR0 + kb + 4);
    T.adjv[0][0] = a0.x; T.adjv[0][1] = a0.y; T.adjv[0][2] = a0.z; T.adjv[0][3] = a0.w;
    T.adjv[0][4] = a1.x; T.adjv[0][5] = a1.y; T.adjv[0][6] = a1.z; T.adjv[0][7] = a1.w;
    float4 b0 = *(const float4*)(adjR1 + kb);
    float4 b1 = *(const float4*)(adjR1 + kb + 4);
    T.adjv[1][0] = b0.x; T.adjv[1][1] = b0.y; T.adjv[1][2] = b0.z; T.adjv[1][3] = b0.w;
    T.adjv[1][4] = b1.x; T.adjv[1][5] = b1.y; T.adjv[1][6] = b1.z; T.adjv[1][7] = b1.w;
}

static __device__ inline void compute_tile(
    const JTile& T, const float* s1v, f32x4 acc[2][4], float* lpart)
{
#pragma unroll
    for (int it = 0; it < 2; ++it) {
        short8 afrag;
        const float s1 = s1v[it];
#pragma unroll
        for (int q = 0; q < 8; ++q) {
            float e = s1 + T.s2v[q];
            e = fmaxf(e, 0.2f * e);              // leaky relu (scale-invariant)
            float p = (T.adjv[it][q] > 0.5f) ? EXP2F(e) : 0.0f;
            lpart[it] += p;
            afrag[q] = f32_to_bf16_bits(p);
        }
#pragma unroll
        for (int ct = 0; ct < 4; ++ct)
            acc[it][ct] = __builtin_amdgcn_mfma_f32_16x16x32_bf16(
                afrag, T.bfrag[ct], acc[it][ct], 0, 0, 0);
    }
}

__global__ __launch_bounds__(256, 4) void gat_main(
    const float* __restrict__ adj, const float* __restrict__ s1s,
    const float* __restrict__ s2s, const unsigned short* __restrict__ hT,
    float* __restrict__ accP, float* __restrict__ lP, int jsNum)
{
    const int bid  = blockIdx.x;
    const int itb  = bid / jsNum;               // 0..127
    const int js   = bid % jsNum;
    const int jlen = N_ / jsNum;
    const int j0   = js * jlen;
    const int i0   = itb * 32;
    const int lane = threadIdx.x & 63;
    const int b    = threadIdx.x >> 6;          // one batch per wave
    const int g    = lane >> 4;
    const int r16  = lane & 15;

    float s1v[2];
    s1v[0] = s1s[b * N_ + i0 + r16];
    s1v[1] = s1s[b * N_ + i0 + 16 + r16];

    f32x4 acc[2][4];
#pragma unroll
    for (int it = 0; it < 2; ++it)
#pragma unroll
        for (int ct = 0; ct < 4; ++ct)
            acc[it][ct] = (f32x4){0.f, 0.f, 0.f, 0.f};
    float lpart[2] = {0.f, 0.f};

    const unsigned short* hTb = hT + (size_t)b * C_ * N_;
    const float* s2b   = s2s + b * N_;
    const float* adjR0 = adj + (size_t)(i0 + r16) * N_;
    const float* adjR1 = adj + (size_t)(i0 + 16 + r16) * N_;
    const int kbase = j0 + g * 8;

    JTile tA, tB;
    load_tile(tA, hTb, s2b, adjR0, adjR1, kbase, r16);
    for (int base = 0; base + 64 <= jlen; base += 64) {
        load_tile(tB, hTb, s2b, adjR0, adjR1, kbase + base + 32, r16);
        compute_tile(tA, s1v, acc, lpart);
        if (base + 64 < jlen)
            load_tile(tA, hTb, s2b, adjR0, adjR1, kbase + base + 64, r16);
        compute_tile(tB, s1v, acc, lpart);
    }

    // l: sum the 4 lane-groups (each covered a distinct k-slice)
#pragma unroll
    for (int it = 0; it < 2; ++it) {
        float v = lpart[it];
        v += __shfl_xor(v, 16, 64);
        v += __shfl_xor(v, 32, 64);
        lpart[it] = v;
    }

    const size_t pb = (size_t)js * B_ + b;
    if (g == 0) {
        lP[pb * N_ + i0 + r16]      = lpart[0];
        lP[pb * N_ + i0 + 16 + r16] = lpart[1];
    }

    float* accBase = accP + pb * (size_t)N_ * C_;
#pragma unroll
    for (int it = 0; it < 2; ++it)
#pragma unroll
        for (int ct = 0; ct < 4; ++ct)
#pragma unroll
            for (int r = 0; r < 4; ++r) {
                const int i = i0 + it * 16 + g * 4 + r;
                const int c = ct * 16 + r16;
                accBase[(size_t)i * C_ + c] = acc[it][ct][r];
            }
}

// ---------------------------------------------------------------------------
// Combine: out = elu( (sum_p acc_p) / (sum_p l_p) ), float4 per thread
// ---------------------------------------------------------------------------
__global__ __launch_bounds__(256) void gat_combine(
    const float* __restrict__ accP, const float* __restrict__ lP,
    float* __restrict__ out, int jsNum)
{
    const int t = blockIdx.x * 256 + threadIdx.x;      // one float4
    const int total4 = B_ * N_ * C_ / 4;
    if (t >= total4) return;
    const int bi = t >> 4;                             // (t*4)/C_
    float4 asum = {0.f, 0.f, 0.f, 0.f};
    float lsum = 0.f;
    for (int p = 0; p < jsNum; ++p) {
        float4 v = ((const float4*)accP)[(size_t)p * total4 + t];
        asum.x += v.x; asum.y += v.y; asum.z += v.z; asum.w += v.w;
        lsum += lP[(size_t)p * (B_ * N_) + bi];
    }
    const float inv = 1.0f / lsum;
    float4 o;
    o.x = asum.x * inv; o.y = asum.y * inv; o.z = asum.z * inv; o.w = asum.w * inv;
    o.x = (o.x > 0.f) ? o.x : (expf(o.x) - 1.f);
    o.y = (o.y > 0.f) ? o.y : (expf(o.y) - 1.f);
    o.z = (o.z > 0.f) ? o.z : (expf(o.z) - 1.f);
    o.w = (o.w > 0.f) ? o.w : (expf(o.w) - 1.f);
    ((float4*)out)[t] = o;
}

// ---------------------------------------------------------------------------
extern "C" void kernel_launch(void* const* d_in, const int* in_sizes, int n_in,
                              void* d_out, int out_size, void* d_ws, size_t ws_size,
                              hipStream_t stream)
{
    const float* h   = (const float*)d_in[0];   // (B,N,C) f32
    const float* adj = (const float*)d_in[1];   // (N,N)   f32
    const float* a   = (const float*)d_in[2];   // (2C,1)  f32
    float* out = (float*)d_out;

    char* ws = (char*)d_ws;
    float* s1s = (float*)ws;                                    // B*N f32
    float* s2s = (float*)(ws + (size_t)B_ * N_ * 4);            // B*N f32
    unsigned short* hT = (unsigned short*)(ws + (size_t)2 * B_ * N_ * 4);
    const size_t lOff = (size_t)2 * B_ * N_ * 4 + (size_t)B_ * C_ * N_ * 2;

    int jsNum = 8;
    while (jsNum > 1) {
        size_t need = lOff + (size_t)jsNum * B_ * N_ * 4
                           + (size_t)jsNum * B_ * N_ * C_ * 4;
        if (need <= ws_size) break;
        jsNum >>= 1;
    }
    float* lP   = (float*)(ws + lOff);
    float* accP = (float*)(ws + lOff + (size_t)jsNum * B_ * N_ * 4);

    gat_prep<<<B_ * (N_ / 64), 256, 0, stream>>>(h, a, s1s, s2s, hT);
    gat_main<<<128 * jsNum, 256, 0, stream>>>(adj, s1s, s2s, hT, accP, lP, jsNum);
    gat_combine<<<(B_ * N_ * C_ / 4 + 255) / 256, 256, 0, stream>>>(accP, lP, out, jsNum);
}

// Round 3
// 197.631 us; speedup vs baseline: 1.1140x; 1.1140x over previous
//
#include <hip/hip_runtime.h>
#include <hip/hip_bf16.h>

#define B_ 4
#define N_ 4096
#define C_ 64

constexpr float LOG2E = 1.44269504088896340736f;

typedef __attribute__((ext_vector_type(8))) short short8;
typedef __attribute__((ext_vector_type(4))) float f32x4;

#if __has_builtin(__builtin_amdgcn_exp2f)
#define EXP2F(x) __builtin_amdgcn_exp2f(x)
#else
#define EXP2F(x) exp2f(x)
#endif

static __device__ inline short f32_to_bf16_bits(float f) {
    union { __hip_bfloat16 h; unsigned short u; } cv;
    cv.h = __float2bfloat16(f);
    return (short)cv.u;
}

// ---------------------------------------------------------------------------
// Fused prep: per (b, 64-row tile):
//   s1[b,i] = (h[b,i,:]@a1)*log2e ; s2 likewise
//   hT[b][c][j] = bf16(h[b][j][c])
// ---------------------------------------------------------------------------
__global__ __launch_bounds__(256) void gat_prep(
    const float* __restrict__ h, const float* __restrict__ a,
    float* __restrict__ s1s, float* __restrict__ s2s,
    unsigned short* __restrict__ hT)
{
    const int bid = blockIdx.x;                 // B * N/64 = 256
    const int b = bid >> 6;
    const int i0 = (bid & 63) * 64;
    __shared__ float tile[64][65];
    const int t = threadIdx.x;
    {
        const int rr = t >> 2;                  // local row (j)
        const int cc = (t & 3) * 16;            // channel chunk
        const float* src = h + ((size_t)(b * N_ + i0 + rr)) * C_ + cc;
        float d1 = 0.f, d2 = 0.f;
#pragma unroll
        for (int k = 0; k < 16; k += 4) {
            float4 v = *(const float4*)(src + k);
            tile[rr][cc + k + 0] = v.x;
            tile[rr][cc + k + 1] = v.y;
            tile[rr][cc + k + 2] = v.z;
            tile[rr][cc + k + 3] = v.w;
            float4 a1 = *(const float4*)(a + cc + k);
            float4 a2 = *(const float4*)(a + C_ + cc + k);
            d1 += v.x * a1.x + v.y * a1.y + v.z * a1.z + v.w * a1.w;
            d2 += v.x * a2.x + v.y * a2.y + v.z * a2.z + v.w * a2.w;
        }
        // 4 consecutive lanes hold partial dots of the same row
        d1 += __shfl_xor(d1, 1, 64); d1 += __shfl_xor(d1, 2, 64);
        d2 += __shfl_xor(d2, 1, 64); d2 += __shfl_xor(d2, 2, 64);
        if ((t & 3) == 0) {
            s1s[b * N_ + i0 + rr] = d1 * LOG2E;
            s2s[b * N_ + i0 + rr] = d2 * LOG2E;
        }
    }
    __syncthreads();
    {
        const int c  = t >> 2;                  // channel
        const int ic = (t & 3) * 16;            // j chunk
        short8 w0, w1;
#pragma unroll
        for (int k = 0; k < 8; ++k)
            w0[k] = f32_to_bf16_bits(tile[ic + k][c]);
#pragma unroll
        for (int k = 0; k < 8; ++k)
            w1[k] = f32_to_bf16_bits(tile[ic + 8 + k][c]);
        unsigned short* dst = hT + ((size_t)(b * C_ + c)) * N_ + i0 + ic;
        *(short8*)(dst)     = w0;
        *(short8*)(dst + 8) = w1;
    }
}

// ---------------------------------------------------------------------------
// Main kernel: masked-softmax numerator + PV with fixed zero max reference.
// ITILE=16 rows per wave (one MFMA i-tile). Grid: 256 i-tiles * jsNum.
// Block: 4 waves = 4 batches sharing adj rows via L1 broadcast. No LDS.
// No explicit double-buffer (round-2 lesson: spill); rely on occupancy.
// ---------------------------------------------------------------------------
__global__ __launch_bounds__(256) void gat_main(
    const float* __restrict__ adj, const float* __restrict__ s1s,
    const float* __restrict__ s2s, const unsigned short* __restrict__ hT,
    float* __restrict__ accP, float* __restrict__ lP, int jsNum)
{
    const int bid  = blockIdx.x;
    const int itb  = bid / jsNum;               // 0..255
    const int js   = bid % jsNum;
    const int jlen = N_ / jsNum;
    const int j0   = js * jlen;
    const int i0   = itb * 16;
    const int lane = threadIdx.x & 63;
    const int b    = threadIdx.x >> 6;          // one batch per wave
    const int g    = lane >> 4;
    const int r16  = lane & 15;

    const float s1 = s1s[b * N_ + i0 + r16];

    f32x4 acc[4];
#pragma unroll
    for (int ct = 0; ct < 4; ++ct)
        acc[ct] = (f32x4){0.f, 0.f, 0.f, 0.f};
    float lpart = 0.f;

    const unsigned short* hTb = hT + (size_t)b * C_ * N_;
    const float* s2b  = s2s + b * N_;
    const float* adjR = adj + (size_t)(i0 + r16) * N_;
    const int kbase = j0 + g * 8;

    for (int jj = 0; jj < jlen; jj += 32) {
        const int kb = kbase + jj;

        short8 bfrag[4];
#pragma unroll
        for (int ct = 0; ct < 4; ++ct)
            bfrag[ct] = *(const short8*)(hTb + (size_t)(ct * 16 + r16) * N_ + kb);

        float4 sa = *(const float4*)(s2b + kb);
        float4 sb = *(const float4*)(s2b + kb + 4);
        float s2v[8] = {sa.x, sa.y, sa.z, sa.w, sb.x, sb.y, sb.z, sb.w};

        float4 a0 = *(const float4*)(adjR + kb);
        float4 a1 = *(const float4*)(adjR + kb + 4);
        float adjv[8] = {a0.x, a0.y, a0.z, a0.w, a1.x, a1.y, a1.z, a1.w};

        short8 afrag;
#pragma unroll
        for (int q = 0; q < 8; ++q) {
            float e = s1 + s2v[q];
            e = fmaxf(e, 0.2f * e);              // leaky relu (scale-invariant)
            float p = (adjv[q] > 0.5f) ? EXP2F(e) : 0.0f;
            lpart += p;
            afrag[q] = f32_to_bf16_bits(p);
        }
#pragma unroll
        for (int ct = 0; ct < 4; ++ct)
            acc[ct] = __builtin_amdgcn_mfma_f32_16x16x32_bf16(
                afrag, bfrag[ct], acc[ct], 0, 0, 0);
    }

    // l: sum the 4 lane-groups (each covered a distinct k-slice)
    {
        float v = lpart;
        v += __shfl_xor(v, 16, 64);
        v += __shfl_xor(v, 32, 64);
        lpart = v;
    }

    const size_t pb = (size_t)js * B_ + b;
    if (g == 0)
        lP[pb * N_ + i0 + r16] = lpart;

    float* accBase = accP + pb * (size_t)N_ * C_;
#pragma unroll
    for (int ct = 0; ct < 4; ++ct)
#pragma unroll
        for (int r = 0; r < 4; ++r) {
            const int i = i0 + g * 4 + r;
            const int c = ct * 16 + r16;
            accBase[(size_t)i * C_ + c] = acc[ct][r];
        }
}

// ---------------------------------------------------------------------------
// Combine: out = elu( (sum_p acc_p) / (sum_p l_p) ), float4 per thread
// ---------------------------------------------------------------------------
__global__ __launch_bounds__(256) void gat_combine(
    const float* __restrict__ accP, const float* __restrict__ lP,
    float* __restrict__ out, int jsNum)
{
    const int t = blockIdx.x * 256 + threadIdx.x;      // one float4
    const int total4 = B_ * N_ * C_ / 4;
    if (t >= total4) return;
    const int bi = t >> 4;                             // (t*4)/C_
    float4 asum = {0.f, 0.f, 0.f, 0.f};
    float lsum = 0.f;
    for (int p = 0; p < jsNum; ++p) {
        float4 v = ((const float4*)accP)[(size_t)p * total4 + t];
        asum.x += v.x; asum.y += v.y; asum.z += v.z; asum.w += v.w;
        lsum += lP[(size_t)p * (B_ * N_) + bi];
    }
    const float inv = 1.0f / lsum;
    float4 o;
    o.x = asum.x * inv; o.y = asum.y * inv; o.z = asum.z * inv; o.w = asum.w * inv;
    o.x = (o.x > 0.f) ? o.x : (expf(o.x) - 1.f);
    o.y = (o.y > 0.f) ? o.y : (expf(o.y) - 1.f);
    o.z = (o.z > 0.f) ? o.z : (expf(o.z) - 1.f);
    o.w = (o.w > 0.f) ? o.w : (expf(o.w) - 1.f);
    ((float4*)out)[t] = o;
}

// ---------------------------------------------------------------------------
extern "C" void kernel_launch(void* const* d_in, const int* in_sizes, int n_in,
                              void* d_out, int out_size, void* d_ws, size_t ws_size,
                              hipStream_t stream)
{
    const float* h   = (const float*)d_in[0];   // (B,N,C) f32
    const float* adj = (const float*)d_in[1];   // (N,N)   f32
    const float* a   = (const float*)d_in[2];   // (2C,1)  f32
    float* out = (float*)d_out;

    char* ws = (char*)d_ws;
    float* s1s = (float*)ws;                                    // B*N f32
    float* s2s = (float*)(ws + (size_t)B_ * N_ * 4);            // B*N f32
    unsigned short* hT = (unsigned short*)(ws + (size_t)2 * B_ * N_ * 4);
    const size_t lOff = (size_t)2 * B_ * N_ * 4 + (size_t)B_ * C_ * N_ * 2;

    int jsNum = 8;
    while (jsNum > 1) {
        size_t need = lOff + (size_t)jsNum * B_ * N_ * 4
                           + (size_t)jsNum * B_ * N_ * C_ * 4;
        if (need <= ws_size) break;
        jsNum >>= 1;
    }
    float* lP   = (float*)(ws + lOff);
    float* accP = (float*)(ws + lOff + (size_t)jsNum * B_ * N_ * 4);

    gat_prep<<<B_ * (N_ / 64), 256, 0, stream>>>(h, a, s1s, s2s, hT);
    gat_main<<<256 * jsNum, 256, 0, stream>>>(adj, s1s, s2s, hT, accP, lP, jsNum);
    gat_combine<<<(B_ * N_ * C_ / 4 + 255) / 256, 256, 0, stream>>>(accP, lP, out, jsNum);
}

// Round 4
// 167.780 us; speedup vs baseline: 1.3122x; 1.1779x over previous
//
#include <hip/hip_runtime.h>
#include <hip/hip_bf16.h>

#define B_ 4
#define N_ 4096
#define C_ 64

constexpr float LOG2E = 1.44269504088896340736f;

typedef __attribute__((ext_vector_type(8))) short short8;
typedef __attribute__((ext_vector_type(4))) float f32x4;

#if __has_builtin(__builtin_amdgcn_exp2f)
#define EXP2F(x) __builtin_amdgcn_exp2f(x)
#else
#define EXP2F(x) exp2f(x)
#endif

static __device__ inline short f32_to_bf16_bits(float f) {
    union { __hip_bfloat16 h; unsigned short u; } cv;
    cv.h = __float2bfloat16(f);
    return (short)cv.u;
}

// ---------------------------------------------------------------------------
// Fused prep: per (b, 64-row tile):
//   s1[b,i] = (h[b,i,:]@a1)*log2e ; s2 likewise
//   hT[b][c][j] = bf16(h[b][j][c])
// ---------------------------------------------------------------------------
__global__ __launch_bounds__(256) void gat_prep(
    const float* __restrict__ h, const float* __restrict__ a,
    float* __restrict__ s1s, float* __restrict__ s2s,
    unsigned short* __restrict__ hT)
{
    const int bid = blockIdx.x;                 // B * N/64 = 256
    const int b = bid >> 6;
    const int i0 = (bid & 63) * 64;
    __shared__ float tile[64][65];
    const int t = threadIdx.x;
    {
        const int rr = t >> 2;                  // local row (j)
        const int cc = (t & 3) * 16;            // channel chunk
        const float* src = h + ((size_t)(b * N_ + i0 + rr)) * C_ + cc;
        float d1 = 0.f, d2 = 0.f;
#pragma unroll
        for (int k = 0; k < 16; k += 4) {
            float4 v = *(const float4*)(src + k);
            tile[rr][cc + k + 0] = v.x;
            tile[rr][cc + k + 1] = v.y;
            tile[rr][cc + k + 2] = v.z;
            tile[rr][cc + k + 3] = v.w;
            float4 a1 = *(const float4*)(a + cc + k);
            float4 a2 = *(const float4*)(a + C_ + cc + k);
            d1 += v.x * a1.x + v.y * a1.y + v.z * a1.z + v.w * a1.w;
            d2 += v.x * a2.x + v.y * a2.y + v.z * a2.z + v.w * a2.w;
        }
        // 4 consecutive lanes hold partial dots of the same row
        d1 += __shfl_xor(d1, 1, 64); d1 += __shfl_xor(d1, 2, 64);
        d2 += __shfl_xor(d2, 1, 64); d2 += __shfl_xor(d2, 2, 64);
        if ((t & 3) == 0) {
            s1s[b * N_ + i0 + rr] = d1 * LOG2E;
            s2s[b * N_ + i0 + rr] = d2 * LOG2E;
        }
    }
    __syncthreads();
    {
        const int c  = t >> 2;                  // channel
        const int ic = (t & 3) * 16;            // j chunk
        short8 w0, w1;
#pragma unroll
        for (int k = 0; k < 8; ++k)
            w0[k] = f32_to_bf16_bits(tile[ic + k][c]);
#pragma unroll
        for (int k = 0; k < 8; ++k)
            w1[k] = f32_to_bf16_bits(tile[ic + 8 + k][c]);
        unsigned short* dst = hT + ((size_t)(b * C_ + c)) * N_ + i0 + ic;
        *(short8*)(dst)     = w0;
        *(short8*)(dst + 8) = w1;
    }
}

// ---------------------------------------------------------------------------
// Main kernel: masked-softmax numerator + PV with fixed zero max reference.
// ITILE=32 rows/wave (2 MFMA i-tiles): balance of round-1 amortization and
// round-3 occupancy. Grid: 128 i-tiles * jsNum = 1024 blocks (16 waves/CU).
// Block: 4 waves = 4 batches sharing adj rows via L1. No LDS, no manual dbuf.
// l computed via ones-MFMA (free pipe) instead of VALU adds.
// ---------------------------------------------------------------------------
__global__ __launch_bounds__(256) void gat_main(
    const float* __restrict__ adj, const float* __restrict__ s1s,
    const float* __restrict__ s2s, const unsigned short* __restrict__ hT,
    float* __restrict__ accP, float* __restrict__ lP, int jsNum)
{
    const int bid  = blockIdx.x;
    const int itb  = bid / jsNum;               // 0..127
    const int js   = bid % jsNum;
    const int jlen = N_ / jsNum;
    const int j0   = js * jlen;
    const int i0   = itb * 32;
    const int lane = threadIdx.x & 63;
    const int b    = threadIdx.x >> 6;          // one batch per wave
    const int g    = lane >> 4;
    const int r16  = lane & 15;

    float s1v[2];
    s1v[0] = s1s[b * N_ + i0 + r16];
    s1v[1] = s1s[b * N_ + i0 + 16 + r16];

    f32x4 acc[2][4];
#pragma unroll
    for (int it = 0; it < 2; ++it)
#pragma unroll
        for (int ct = 0; ct < 4; ++ct)
            acc[it][ct] = (f32x4){0.f, 0.f, 0.f, 0.f};
    f32x4 accL[2];
    accL[0] = (f32x4){0.f, 0.f, 0.f, 0.f};
    accL[1] = (f32x4){0.f, 0.f, 0.f, 0.f};

    short8 ones;
#pragma unroll
    for (int q = 0; q < 8; ++q) ones[q] = (short)0x3F80;   // bf16(1.0)

    const unsigned short* hTb = hT + (size_t)b * C_ * N_;
    const float* s2b   = s2s + b * N_;
    const float* adjR0 = adj + (size_t)(i0 + r16) * N_;
    const float* adjR1 = adj + (size_t)(i0 + 16 + r16) * N_;
    const int kbase = j0 + g * 8;

    for (int jj = 0; jj < jlen; jj += 32) {
        const int kb = kbase + jj;

        short8 bfrag[4];
#pragma unroll
        for (int ct = 0; ct < 4; ++ct)
            bfrag[ct] = *(const short8*)(hTb + (size_t)(ct * 16 + r16) * N_ + kb);

        float4 sa = *(const float4*)(s2b + kb);
        float4 sb = *(const float4*)(s2b + kb + 4);
        float s2v[8] = {sa.x, sa.y, sa.z, sa.w, sb.x, sb.y, sb.z, sb.w};

        float4 a00 = *(const float4*)(adjR0 + kb);
        float4 a01 = *(const float4*)(adjR0 + kb + 4);
        float4 a10 = *(const float4*)(adjR1 + kb);
        float4 a11 = *(const float4*)(adjR1 + kb + 4);
        float adjv[2][8] = {
            {a00.x, a00.y, a00.z, a00.w, a01.x, a01.y, a01.z, a01.w},
            {a10.x, a10.y, a10.z, a10.w, a11.x, a11.y, a11.z, a11.w}};

#pragma unroll
        for (int it = 0; it < 2; ++it) {
            const float s1 = s1v[it];
            short8 afrag;
#pragma unroll
            for (int q = 0; q < 8; ++q) {
                float e = s1 + s2v[q];
                e = fmaxf(e, 0.2f * e);          // leaky relu (scale-invariant)
                float p = (adjv[it][q] > 0.5f) ? EXP2F(e) : 0.0f;
                afrag[q] = f32_to_bf16_bits(p);
            }
#pragma unroll
            for (int ct = 0; ct < 4; ++ct)
                acc[it][ct] = __builtin_amdgcn_mfma_f32_16x16x32_bf16(
                    afrag, bfrag[ct], acc[it][ct], 0, 0, 0);
            accL[it] = __builtin_amdgcn_mfma_f32_16x16x32_bf16(
                afrag, ones, accL[it], 0, 0, 0);
        }
    }

    const size_t pb = (size_t)js * B_ + b;
    // accL[it][r] at any column holds rowsum(row = g*4+r); col r16==0 writes.
    if (r16 == 0) {
#pragma unroll
        for (int it = 0; it < 2; ++it)
#pragma unroll
            for (int r = 0; r < 4; ++r)
                lP[pb * N_ + i0 + it * 16 + g * 4 + r] = accL[it][r];
    }

    float* accBase = accP + pb * (size_t)N_ * C_;
#pragma unroll
    for (int it = 0; it < 2; ++it)
#pragma unroll
        for (int ct = 0; ct < 4; ++ct)
#pragma unroll
            for (int r = 0; r < 4; ++r) {
                const int i = i0 + it * 16 + g * 4 + r;
                const int c = ct * 16 + r16;
                accBase[(size_t)i * C_ + c] = acc[it][ct][r];
            }
}

// ---------------------------------------------------------------------------
// Combine: out = elu( (sum_p acc_p) / (sum_p l_p) ), float4 per thread
// ---------------------------------------------------------------------------
__global__ __launch_bounds__(256) void gat_combine(
    const float* __restrict__ accP, const float* __restrict__ lP,
    float* __restrict__ out, int jsNum)
{
    const int t = blockIdx.x * 256 + threadIdx.x;      // one float4
    const int total4 = B_ * N_ * C_ / 4;
    if (t >= total4) return;
    const int bi = t >> 4;                             // (t*4)/C_
    float4 asum = {0.f, 0.f, 0.f, 0.f};
    float lsum = 0.f;
    for (int p = 0; p < jsNum; ++p) {
        float4 v = ((const float4*)accP)[(size_t)p * total4 + t];
        asum.x += v.x; asum.y += v.y; asum.z += v.z; asum.w += v.w;
        lsum += lP[(size_t)p * (B_ * N_) + bi];
    }
    const float inv = 1.0f / lsum;
    float4 o;
    o.x = asum.x * inv; o.y = asum.y * inv; o.z = asum.z * inv; o.w = asum.w * inv;
    o.x = (o.x > 0.f) ? o.x : (expf(o.x) - 1.f);
    o.y = (o.y > 0.f) ? o.y : (expf(o.y) - 1.f);
    o.z = (o.z > 0.f) ? o.z : (expf(o.z) - 1.f);
    o.w = (o.w > 0.f) ? o.w : (expf(o.w) - 1.f);
    ((float4*)out)[t] = o;
}

// ---------------------------------------------------------------------------
extern "C" void kernel_launch(void* const* d_in, const int* in_sizes, int n_in,
                              void* d_out, int out_size, void* d_ws, size_t ws_size,
                              hipStream_t stream)
{
    const float* h   = (const float*)d_in[0];   // (B,N,C) f32
    const float* adj = (const float*)d_in[1];   // (N,N)   f32
    const float* a   = (const float*)d_in[2];   // (2C,1)  f32
    float* out = (float*)d_out;

    char* ws = (char*)d_ws;
    float* s1s = (float*)ws;                                    // B*N f32
    float* s2s = (float*)(ws + (size_t)B_ * N_ * 4);            // B*N f32
    unsigned short* hT = (unsigned short*)(ws + (size_t)2 * B_ * N_ * 4);
    const size_t lOff = (size_t)2 * B_ * N_ * 4 + (size_t)B_ * C_ * N_ * 2;

    int jsNum = 8;
    while (jsNum > 1) {
        size_t need = lOff + (size_t)jsNum * B_ * N_ * 4
                           + (size_t)jsNum * B_ * N_ * C_ * 4;
        if (need <= ws_size) break;
        jsNum >>= 1;
    }
    float* lP   = (float*)(ws + lOff);
    float* accP = (float*)(ws + lOff + (size_t)jsNum * B_ * N_ * 4);

    gat_prep<<<B_ * (N_ / 64), 256, 0, stream>>>(h, a, s1s, s2s, hT);
    gat_main<<<128 * jsNum, 256, 0, stream>>>(adj, s1s, s2s, hT, accP, lP, jsNum);
    gat_combine<<<(B_ * N_ * C_ / 4 + 255) / 256, 256, 0, stream>>>(accP, lP, out, jsNum);
}